// Round 1
// baseline (2017.952 us; speedup 1.0000x reference)
//
#include <hip/hip_runtime.h>
#include <hip/hip_bf16.h>

using f32x4 = __attribute__((ext_vector_type(4))) float;
using i64 = long long;

#define E4M3_MAX 448.0f
#define AS1 __attribute__((address_space(1)))
#define AS3 __attribute__((address_space(3)))

__device__ __forceinline__ float clip448(float v) {
  return fminf(fmaxf(v, -E4M3_MAX), E4M3_MAX);
}

__device__ __forceinline__ void gld_lds16(const void* g, void* l) {
  __builtin_amdgcn_global_load_lds((const AS1 void*)g, (AS3 void*)l, 16, 0, 0);
}

// ---------------- init ----------------
__global__ void init_ws_kernel(unsigned int* amax) {
  amax[0] = 0u;
  amax[1] = 0u;
}

// ---------------- amax reduction ----------------
__global__ void amax_kernel(const float* __restrict__ x, long n4,
                            unsigned int* __restrict__ amax_out) {
  long i0 = (long)blockIdx.x * blockDim.x + threadIdx.x;
  long stride = (long)gridDim.x * blockDim.x;
  const float4* x4 = (const float4*)x;
  float m = 0.f;
  for (long i = i0; i < n4; i += stride) {
    float4 v = x4[i];
    m = fmaxf(m, fmaxf(fmaxf(fabsf(v.x), fabsf(v.y)), fmaxf(fabsf(v.z), fabsf(v.w))));
  }
#pragma unroll
  for (int off = 32; off >= 1; off >>= 1)
    m = fmaxf(m, __shfl_xor(m, off));
  __shared__ float wmax[8];
  int wid = threadIdx.x >> 6;
  if ((threadIdx.x & 63) == 0) wmax[wid] = m;
  __syncthreads();
  if (threadIdx.x == 0) {
    int nw = blockDim.x >> 6;
    float bm = wmax[0];
    for (int w = 1; w < nw; ++w) bm = fmaxf(bm, wmax[w]);
    atomicMax(amax_out, __float_as_uint(bm));  // all vals >= 0: uint order == float order
  }
}

// ---------------- delayed-scaling scale computation ----------------
__global__ void scale_kernel(const unsigned int* __restrict__ amax,
                             const float* __restrict__ scale_x,
                             const float* __restrict__ hist_x,
                             const float* __restrict__ scale_k,
                             const float* __restrict__ hist_k,
                             int hl, float* __restrict__ scales) {
  if (threadIdx.x != 0) return;
  // x
  float ax = __uint_as_float(amax[0]);
  for (int i = 0; i < hl - 1; ++i) ax = fmaxf(ax, hist_x[i]);
  float sfx = E4M3_MAX / ax;
  if (!(ax > 0.f && isfinite(ax))) sfx = 1.f / scale_x[0];
  float sx = 1.f / sfx;
  // k
  float ak = __uint_as_float(amax[1]);
  for (int i = 0; i < hl - 1; ++i) ak = fmaxf(ak, hist_k[i]);
  float sfk = E4M3_MAX / ak;
  if (!(ak > 0.f && isfinite(ak))) sfk = 1.f / scale_k[0];
  float sk = 1.f / sfk;

  scales[0] = sx;
  scales[1] = sk;
  scales[2] = sx * sk;
}

// ---------------- quantize x -> fp8 A[M][K] ----------------
__global__ void quant_x_kernel(const float* __restrict__ x,
                               unsigned int* __restrict__ q,
                               const float* __restrict__ scales, long n4) {
  float s = scales[0];
  long i0 = (long)blockIdx.x * blockDim.x + threadIdx.x;
  long stride = (long)gridDim.x * blockDim.x;
  const float4* x4 = (const float4*)x;
  for (long i = i0; i < n4; i += stride) {
    float4 v = x4[i];
    int p = 0;
    p = __builtin_amdgcn_cvt_pk_fp8_f32(clip448(v.x / s), clip448(v.y / s), p, false);
    p = __builtin_amdgcn_cvt_pk_fp8_f32(clip448(v.z / s), clip448(v.w / s), p, true);
    q[i] = (unsigned int)p;
  }
}

// ---------------- transpose-quantize W[K][N] -> fp8 B^T[N][K] ----------------
__global__ void quant_kT_kernel(const float* __restrict__ w,
                                unsigned char* __restrict__ bt,
                                const float* __restrict__ scales, int K, int N) {
  float s = scales[1];
  int k0 = blockIdx.y * 64;
  int n0 = blockIdx.x * 64;
  __shared__ unsigned int lds[64][17];  // [n_local][k_word]; 17 breaks bank alias
  int t = threadIdx.x;
  int nb = t & 15;   // n-block (4 cols)
  int kb = t >> 4;   // k-block (4 rows)
  float fa[4][4];
#pragma unroll
  for (int j = 0; j < 4; ++j) {
    float4 v = *(const float4*)&w[(long)(k0 + kb * 4 + j) * N + n0 + nb * 4];
    fa[j][0] = v.x; fa[j][1] = v.y; fa[j][2] = v.z; fa[j][3] = v.w;
  }
#pragma unroll
  for (int i = 0; i < 4; ++i) {  // pack along K while converting: free transpose
    int p = 0;
    p = __builtin_amdgcn_cvt_pk_fp8_f32(clip448(fa[0][i] / s), clip448(fa[1][i] / s), p, false);
    p = __builtin_amdgcn_cvt_pk_fp8_f32(clip448(fa[2][i] / s), clip448(fa[3][i] / s), p, true);
    lds[nb * 4 + i][kb] = (unsigned int)p;
  }
  __syncthreads();
  int nl = t >> 2, kq = t & 3;
  uint4 o;
  o.x = lds[nl][kq * 4 + 0];
  o.y = lds[nl][kq * 4 + 1];
  o.z = lds[nl][kq * 4 + 2];
  o.w = lds[nl][kq * 4 + 3];
  *(uint4*)&bt[(long)(n0 + nl) * K + k0 + kq * 16] = o;
}

// ---------------- fp8 GEMM + scale + bias + gelu ----------------
// C[M][N] = gelu( (A[M][K] @ B^T[N][K]^T) * s_xk + bf16(bias) )
// 128x128 tile, BK=64, 256 threads (4 waves, 2x2), mfma_f32_16x16x32_fp8_fp8
#define GBM 128
#define GBN 128
#define GBK 64

__global__ __launch_bounds__(256, 2) void gemm_fp8_kernel(
    const unsigned char* __restrict__ Aq, const unsigned char* __restrict__ Bq,
    const float* __restrict__ bias, const float* __restrict__ scales,
    float* __restrict__ C, int M, int N, int K) {
  __shared__ unsigned char lA[GBM * GBK];
  __shared__ unsigned char lB[GBN * GBK];
  const float s_xk = scales[2];

  const int t = threadIdx.x;
  const int lane = t & 63;
  const int wid = t >> 6;
  const int wm = wid >> 1, wn = wid & 1;
  const int m0 = blockIdx.y * GBM;
  const int n0 = blockIdx.x * GBN;

  f32x4 acc[4][4];
#pragma unroll
  for (int i = 0; i < 4; ++i)
#pragma unroll
    for (int j = 0; j < 4; ++j)
#pragma unroll
      for (int r = 0; r < 4; ++r) acc[i][j][r] = 0.f;

  // staging geometry: tile byte off = t*16 (+4096 for 2nd call); row=off/64, col=off%64
  const int r0 = (t * 16) >> 6;
  const int c0 = (t * 16) & 63;

  for (int k0 = 0; k0 < K; k0 += GBK) {
    const unsigned char* ga = Aq + (long)(m0 + r0) * K + k0 + c0;
    const unsigned char* gb = Bq + (long)(n0 + r0) * K + k0 + c0;
    gld_lds16(ga, &lA[wid * 1024]);
    gld_lds16(ga + (long)64 * K, &lA[wid * 1024 + 4096]);
    gld_lds16(gb, &lB[wid * 1024]);
    gld_lds16(gb + (long)64 * K, &lB[wid * 1024 + 4096]);
    __syncthreads();

#pragma unroll
    for (int kk = 0; kk < GBK; kk += 32) {
      i64 afrag[4], bfrag[4];
#pragma unroll
      for (int i = 0; i < 4; ++i) {
        int ar = wm * 64 + i * 16 + (lane & 15);
        afrag[i] = *(const i64*)&lA[ar * GBK + kk + (lane >> 4) * 8];
        int br = wn * 64 + i * 16 + (lane & 15);
        bfrag[i] = *(const i64*)&lB[br * GBK + kk + (lane >> 4) * 8];
      }
#pragma unroll
      for (int i = 0; i < 4; ++i)
#pragma unroll
        for (int j = 0; j < 4; ++j)
          acc[i][j] = __builtin_amdgcn_mfma_f32_16x16x32_fp8_fp8(
              afrag[i], bfrag[j], acc[i][j], 0, 0, 0);
    }
    __syncthreads();
  }

  // epilogue: scale, bias (bf16-rounded), tanh-gelu
  float bv[4];
#pragma unroll
  for (int j = 0; j < 4; ++j) {
    int col = n0 + wn * 64 + j * 16 + (lane & 15);
    bv[j] = __bfloat162float(__float2bfloat16(bias[col]));
  }
#pragma unroll
  for (int i = 0; i < 4; ++i) {
    int rowb = m0 + wm * 64 + i * 16 + ((lane >> 4) << 2);
#pragma unroll
    for (int j = 0; j < 4; ++j) {
      int col = n0 + wn * 64 + j * 16 + (lane & 15);
#pragma unroll
      for (int r = 0; r < 4; ++r) {
        float v = acc[i][j][r] * s_xk + bv[j];
        float g = 0.5f * v *
                  (1.0f + tanhf(0.7978845608028654f * (v + 0.044715f * v * v * v)));
        C[(long)(rowb + r) * N + col] = g;
      }
    }
  }
}

// ---------------- launch ----------------
extern "C" void kernel_launch(void* const* d_in, const int* in_sizes, int n_in,
                              void* d_out, int out_size, void* d_ws, size_t ws_size,
                              hipStream_t stream) {
  const float* inputs = (const float*)d_in[0];
  const float* kernelw = (const float*)d_in[1];
  const float* bias = (const float*)d_in[2];
  const float* input_scale = (const float*)d_in[3];
  const float* input_hist = (const float*)d_in[4];
  const float* kernel_scale = (const float*)d_in[5];
  const float* kernel_hist = (const float*)d_in[6];

  const int F = in_sizes[2];            // 16384
  const int D = in_sizes[1] / F;        // 4096
  const long M = (long)in_sizes[0] / D; // 8192
  const int HL = in_sizes[4];           // 16
  const int N = F, K = D;

  unsigned int* amax = (unsigned int*)d_ws;
  float* scales = (float*)((char*)d_ws + 16);
  unsigned char* Aq = (unsigned char*)d_ws + 64;
  unsigned char* Bq = Aq + (size_t)M * K;

  float* C = (float*)d_out;

  init_ws_kernel<<<1, 1, 0, stream>>>(amax);
  amax_kernel<<<2048, 256, 0, stream>>>(inputs, (long)M * K / 4, &amax[0]);
  amax_kernel<<<2048, 256, 0, stream>>>(kernelw, (long)K * N / 4, &amax[1]);
  scale_kernel<<<1, 64, 0, stream>>>(amax, input_scale, input_hist, kernel_scale,
                                     kernel_hist, HL, scales);
  quant_x_kernel<<<2048, 256, 0, stream>>>(inputs, (unsigned int*)Aq, scales,
                                           (long)M * K / 4);
  quant_kT_kernel<<<dim3(N / 64, K / 64), 256, 0, stream>>>(kernelw, Bq, scales, K, N);
  gemm_fp8_kernel<<<dim3(N / GBN, M / GBM), 256, 0, stream>>>(Aq, Bq, bias, scales, C,
                                                              (int)M, N, K);
}

// Round 2
// 945.020 us; speedup vs baseline: 2.1354x; 2.1354x over previous
//
#include <hip/hip_runtime.h>
#include <hip/hip_bf16.h>

using f32x4 = __attribute__((ext_vector_type(4))) float;
typedef long long i64;
typedef __attribute__((ext_vector_type(2))) long long i64x2;

#define E4M3_MAX 448.0f
#define AS1 __attribute__((address_space(1)))
#define AS3 __attribute__((address_space(3)))

__device__ __forceinline__ float clip448(float v) {
  return fminf(fmaxf(v, -E4M3_MAX), E4M3_MAX);
}

__device__ __forceinline__ void gld_lds16(const void* g, void* l) {
  __builtin_amdgcn_global_load_lds((const AS1 void*)g, (AS3 void*)l, 16, 0, 0);
}

// ---------------- init ----------------
__global__ void init_ws_kernel(unsigned int* amax) {
  amax[0] = 0u;
  amax[1] = 0u;
}

// ---------------- amax reduction ----------------
__global__ void amax_kernel(const float* __restrict__ x, long n4,
                            unsigned int* __restrict__ amax_out) {
  long i0 = (long)blockIdx.x * blockDim.x + threadIdx.x;
  long stride = (long)gridDim.x * blockDim.x;
  const float4* x4 = (const float4*)x;
  float m = 0.f;
  for (long i = i0; i < n4; i += stride) {
    float4 v = x4[i];
    m = fmaxf(m, fmaxf(fmaxf(fabsf(v.x), fabsf(v.y)), fmaxf(fabsf(v.z), fabsf(v.w))));
  }
#pragma unroll
  for (int off = 32; off >= 1; off >>= 1)
    m = fmaxf(m, __shfl_xor(m, off));
  __shared__ float wmax[8];
  int wid = threadIdx.x >> 6;
  if ((threadIdx.x & 63) == 0) wmax[wid] = m;
  __syncthreads();
  if (threadIdx.x == 0) {
    int nw = blockDim.x >> 6;
    float bm = wmax[0];
    for (int w = 1; w < nw; ++w) bm = fmaxf(bm, wmax[w]);
    atomicMax(amax_out, __float_as_uint(bm));  // vals >= 0: uint order == float order
  }
}

// ---------------- delayed-scaling scale computation ----------------
__global__ void scale_kernel(const unsigned int* __restrict__ amax,
                             const float* __restrict__ scale_x,
                             const float* __restrict__ hist_x,
                             const float* __restrict__ scale_k,
                             const float* __restrict__ hist_k,
                             int hl, float* __restrict__ scales) {
  if (threadIdx.x != 0) return;
  float ax = __uint_as_float(amax[0]);
  for (int i = 0; i < hl - 1; ++i) ax = fmaxf(ax, hist_x[i]);
  float sfx = E4M3_MAX / ax;
  if (!(ax > 0.f && isfinite(ax))) sfx = 1.f / scale_x[0];
  float sx = 1.f / sfx;
  float ak = __uint_as_float(amax[1]);
  for (int i = 0; i < hl - 1; ++i) ak = fmaxf(ak, hist_k[i]);
  float sfk = E4M3_MAX / ak;
  if (!(ak > 0.f && isfinite(ak))) sfk = 1.f / scale_k[0];
  float sk = 1.f / sfk;
  scales[0] = sx;
  scales[1] = sk;
  scales[2] = sx * sk;
}

// Tile layout (both operands): per (row-block 128 × k-block 64) tile, 8192 B
// contiguous. Chunk index c = g*64 + l (g=row-group 0..7, l=lane 0..63), 16 B:
//   bytes 0-7 : op[row = g*16 + (l&15)][k = (l>>4)*8 + 0..7]
//   bytes 8-15: op[row = g*16 + (l&15)][k = 32 + (l>>4)*8 + 0..7]
// This is exactly the mfma_f32_16x16x32_fp8_fp8 per-lane fragment pair, so the
// GEMM's LDS reads are single conflict-free ds_read_b128 at lane*16.

// ---------------- quantize x -> tiled fp8 A ----------------
__global__ void quant_x_kernel(const float* __restrict__ x,
                               unsigned char* __restrict__ Aq,
                               const float* __restrict__ scales, int K) {
  const float s = scales[0];
  const int kt = blockIdx.x, mt = blockIdx.y, nkt = gridDim.x;
  __shared__ float lt[128][68];
  const int t = threadIdx.x;
  const float* src = x + (size_t)mt * 128 * K + (size_t)kt * 64;
#pragma unroll
  for (int it = 0; it < 8; ++it) {
    int row = it * 16 + (t >> 4);
    int c4 = (t & 15) * 4;
    float4 v = *(const float4*)&src[(size_t)row * K + c4];
    lt[row][c4 + 0] = v.x; lt[row][c4 + 1] = v.y;
    lt[row][c4 + 2] = v.z; lt[row][c4 + 3] = v.w;
  }
  __syncthreads();
  uint4* out = (uint4*)(Aq + ((size_t)mt * nkt + kt) * 8192);
#pragma unroll
  for (int cc = 0; cc < 2; ++cc) {
    int c = t * 2 + cc;
    int g = c >> 6, l = c & 63;
    int row = g * 16 + (l & 15);
    int e0 = (l >> 4) * 8;
    unsigned int w[4];
#pragma unroll
    for (int h = 0; h < 2; ++h) {
      int b = e0 + h * 32;
      int p0 = 0, p1 = 0;
      p0 = __builtin_amdgcn_cvt_pk_fp8_f32(clip448(lt[row][b+0] / s), clip448(lt[row][b+1] / s), p0, false);
      p0 = __builtin_amdgcn_cvt_pk_fp8_f32(clip448(lt[row][b+2] / s), clip448(lt[row][b+3] / s), p0, true);
      p1 = __builtin_amdgcn_cvt_pk_fp8_f32(clip448(lt[row][b+4] / s), clip448(lt[row][b+5] / s), p1, false);
      p1 = __builtin_amdgcn_cvt_pk_fp8_f32(clip448(lt[row][b+6] / s), clip448(lt[row][b+7] / s), p1, true);
      w[h * 2] = (unsigned int)p0;
      w[h * 2 + 1] = (unsigned int)p1;
    }
    out[c] = make_uint4(w[0], w[1], w[2], w[3]);
  }
}

// ---------------- transpose-quantize W[K][N] -> tiled fp8 B ----------------
__global__ void quant_k_kernel(const float* __restrict__ w,
                               unsigned char* __restrict__ Bq,
                               const float* __restrict__ scales, int N) {
  const float s = scales[1];
  const int kt = blockIdx.x, nt = blockIdx.y, nkt = gridDim.x;
  __shared__ float lt[64][132];
  const int t = threadIdx.x;
  const float* src = w + (size_t)kt * 64 * N + (size_t)nt * 128;
#pragma unroll
  for (int it = 0; it < 8; ++it) {
    int row = it * 8 + (t >> 5);
    int c4 = (t & 31) * 4;
    float4 v = *(const float4*)&src[(size_t)row * N + c4];
    lt[row][c4 + 0] = v.x; lt[row][c4 + 1] = v.y;
    lt[row][c4 + 2] = v.z; lt[row][c4 + 3] = v.w;
  }
  __syncthreads();
  uint4* out = (uint4*)(Bq + ((size_t)nt * nkt + kt) * 8192);
#pragma unroll
  for (int cc = 0; cc < 2; ++cc) {
    int c = t * 2 + cc;
    int g = c >> 6, l = c & 63;
    int nl = g * 16 + (l & 15);
    int e0 = (l >> 4) * 8;
    unsigned int w4[4];
#pragma unroll
    for (int h = 0; h < 2; ++h) {
      int b = e0 + h * 32;
      int p0 = 0, p1 = 0;
      p0 = __builtin_amdgcn_cvt_pk_fp8_f32(clip448(lt[b+0][nl] / s), clip448(lt[b+1][nl] / s), p0, false);
      p0 = __builtin_amdgcn_cvt_pk_fp8_f32(clip448(lt[b+2][nl] / s), clip448(lt[b+3][nl] / s), p0, true);
      p1 = __builtin_amdgcn_cvt_pk_fp8_f32(clip448(lt[b+4][nl] / s), clip448(lt[b+5][nl] / s), p1, false);
      p1 = __builtin_amdgcn_cvt_pk_fp8_f32(clip448(lt[b+6][nl] / s), clip448(lt[b+7][nl] / s), p1, true);
      w4[h * 2] = (unsigned int)p0;
      w4[h * 2 + 1] = (unsigned int)p1;
    }
    out[c] = make_uint4(w4[0], w4[1], w4[2], w4[3]);
  }
}

// ---------------- fp8 GEMM + scale + bias + gelu ----------------
// 128x128 tile, BK=64, 256 threads (4 waves, 2x2), tiles pre-packed contiguous.
__global__ __launch_bounds__(256, 4) void gemm_fp8_kernel(
    const unsigned char* __restrict__ Aq, const unsigned char* __restrict__ Bq,
    const float* __restrict__ bias, const float* __restrict__ scales,
    float* __restrict__ C, int M, int N, int K) {
  __shared__ __align__(16) unsigned char lA[8192];
  __shared__ __align__(16) unsigned char lB[8192];
  const float s_xk = scales[2];
  const int nkt = K >> 6;
  const int t = threadIdx.x;
  const int lane = t & 63;
  const int wid = t >> 6;
  const int wm = wid >> 1, wn = wid & 1;

  const unsigned char* ga = Aq + (size_t)blockIdx.y * nkt * 8192 + t * 16;
  const unsigned char* gb = Bq + (size_t)blockIdx.x * nkt * 8192 + t * 16;

  f32x4 acc[4][4];
#pragma unroll
  for (int i = 0; i < 4; ++i)
#pragma unroll
    for (int j = 0; j < 4; ++j)
#pragma unroll
      for (int r = 0; r < 4; ++r) acc[i][j][r] = 0.f;

  for (int kt = 0; kt < nkt; ++kt) {
    gld_lds16(ga,        &lA[wid * 1024]);
    gld_lds16(ga + 4096, &lA[wid * 1024 + 4096]);
    gld_lds16(gb,        &lB[wid * 1024]);
    gld_lds16(gb + 4096, &lB[wid * 1024 + 4096]);
    ga += 8192;
    gb += 8192;
    __syncthreads();

    i64x2 av[4], bv[4];
#pragma unroll
    for (int i = 0; i < 4; ++i)
      av[i] = *(const i64x2*)&lA[(wm * 4 + i) * 1024 + lane * 16];
#pragma unroll
    for (int j = 0; j < 4; ++j)
      bv[j] = *(const i64x2*)&lB[(wn * 4 + j) * 1024 + lane * 16];

#pragma unroll
    for (int i = 0; i < 4; ++i)
#pragma unroll
      for (int j = 0; j < 4; ++j)
        acc[i][j] = __builtin_amdgcn_mfma_f32_16x16x32_fp8_fp8(
            av[i].x, bv[j].x, acc[i][j], 0, 0, 0);
#pragma unroll
    for (int i = 0; i < 4; ++i)
#pragma unroll
      for (int j = 0; j < 4; ++j)
        acc[i][j] = __builtin_amdgcn_mfma_f32_16x16x32_fp8_fp8(
            av[i].y, bv[j].y, acc[i][j], 0, 0, 0);
    __syncthreads();
  }

  const int m0 = blockIdx.y * 128;
  const int n0 = blockIdx.x * 128;
  float bv4[4];
#pragma unroll
  for (int j = 0; j < 4; ++j) {
    int col = n0 + wn * 64 + j * 16 + (lane & 15);
    bv4[j] = __bfloat162float(__float2bfloat16(bias[col]));
  }
#pragma unroll
  for (int i = 0; i < 4; ++i) {
    int rowb = m0 + wm * 64 + i * 16 + ((lane >> 4) << 2);
#pragma unroll
    for (int j = 0; j < 4; ++j) {
      int col = n0 + wn * 64 + j * 16 + (lane & 15);
#pragma unroll
      for (int r = 0; r < 4; ++r) {
        float v = acc[i][j][r] * s_xk + bv4[j];
        float g = 0.5f * v *
                  (1.0f + tanhf(0.7978845608028654f * (v + 0.044715f * v * v * v)));
        C[(size_t)(rowb + r) * N + col] = g;
      }
    }
  }
}

// ---------------- launch ----------------
extern "C" void kernel_launch(void* const* d_in, const int* in_sizes, int n_in,
                              void* d_out, int out_size, void* d_ws, size_t ws_size,
                              hipStream_t stream) {
  const float* inputs = (const float*)d_in[0];
  const float* kernelw = (const float*)d_in[1];
  const float* bias = (const float*)d_in[2];
  const float* input_scale = (const float*)d_in[3];
  const float* input_hist = (const float*)d_in[4];
  const float* kernel_scale = (const float*)d_in[5];
  const float* kernel_hist = (const float*)d_in[6];

  const int F = in_sizes[2];             // 16384
  const int D = in_sizes[1] / F;         // 4096
  const long M = (long)in_sizes[0] / D;  // 8192
  const int HL = in_sizes[4];            // 16
  const int N = F, K = D;

  unsigned int* amax = (unsigned int*)d_ws;
  float* scales = (float*)((char*)d_ws + 16);
  unsigned char* Aq = (unsigned char*)d_ws + 64;
  unsigned char* Bq = Aq + (size_t)M * K;

  float* C = (float*)d_out;

  init_ws_kernel<<<1, 1, 0, stream>>>(amax);
  amax_kernel<<<2048, 256, 0, stream>>>(inputs, (long)M * K / 4, &amax[0]);
  amax_kernel<<<2048, 256, 0, stream>>>(kernelw, (long)K * N / 4, &amax[1]);
  scale_kernel<<<1, 64, 0, stream>>>(amax, input_scale, input_hist, kernel_scale,
                                     kernel_hist, HL, scales);
  quant_x_kernel<<<dim3(K / 64, M / 128), 256, 0, stream>>>(inputs, Aq, scales, K);
  quant_k_kernel<<<dim3(K / 64, N / 128), 256, 0, stream>>>(kernelw, Bq, scales, N);
  gemm_fp8_kernel<<<dim3(N / 128, M / 128), 256, 0, stream>>>(Aq, Bq, bias, scales, C,
                                                              (int)M, N, K);
}

// Round 3
// 845.799 us; speedup vs baseline: 2.3859x; 1.1173x over previous
//
#include <hip/hip_runtime.h>
#include <hip/hip_bf16.h>

typedef __attribute__((ext_vector_type(4))) int i32x4;
typedef __attribute__((ext_vector_type(8))) int i32x8;
typedef __attribute__((ext_vector_type(16))) float f32x16;

#define E4M3_MAX 448.0f
#define AS1 __attribute__((address_space(1)))
#define AS3 __attribute__((address_space(3)))

__device__ __forceinline__ float clip448(float v) {
  return fminf(fmaxf(v, -E4M3_MAX), E4M3_MAX);
}

__device__ __forceinline__ void gld_lds16(const void* g, void* l) {
  __builtin_amdgcn_global_load_lds((const AS1 void*)g, (AS3 void*)l, 16, 0, 0);
}

// ---------------- init ----------------
__global__ void init_ws_kernel(unsigned int* amax) {
  amax[0] = 0u;
  amax[1] = 0u;
}

// ---------------- amax reduction ----------------
__global__ void amax_kernel(const float* __restrict__ x, long n4,
                            unsigned int* __restrict__ amax_out) {
  long i0 = (long)blockIdx.x * blockDim.x + threadIdx.x;
  long stride = (long)gridDim.x * blockDim.x;
  const float4* x4 = (const float4*)x;
  float m = 0.f;
  for (long i = i0; i < n4; i += stride) {
    float4 v = x4[i];
    m = fmaxf(m, fmaxf(fmaxf(fabsf(v.x), fabsf(v.y)), fmaxf(fabsf(v.z), fabsf(v.w))));
  }
#pragma unroll
  for (int off = 32; off >= 1; off >>= 1)
    m = fmaxf(m, __shfl_xor(m, off));
  __shared__ float wmax[8];
  int wid = threadIdx.x >> 6;
  if ((threadIdx.x & 63) == 0) wmax[wid] = m;
  __syncthreads();
  if (threadIdx.x == 0) {
    int nw = blockDim.x >> 6;
    float bm = wmax[0];
    for (int w = 1; w < nw; ++w) bm = fmaxf(bm, wmax[w]);
    atomicMax(amax_out, __float_as_uint(bm));  // vals >= 0: uint order == float order
  }
}

// ---------------- delayed-scaling scale computation ----------------
__global__ void scale_kernel(const unsigned int* __restrict__ amax,
                             const float* __restrict__ scale_x,
                             const float* __restrict__ hist_x,
                             const float* __restrict__ scale_k,
                             const float* __restrict__ hist_k,
                             int hl, float* __restrict__ scales) {
  if (threadIdx.x != 0) return;
  float ax = __uint_as_float(amax[0]);
  for (int i = 0; i < hl - 1; ++i) ax = fmaxf(ax, hist_x[i]);
  float sfx = E4M3_MAX / ax;
  if (!(ax > 0.f && isfinite(ax))) sfx = 1.f / scale_x[0];
  float sx = 1.f / sfx;
  float ak = __uint_as_float(amax[1]);
  for (int i = 0; i < hl - 1; ++i) ak = fmaxf(ak, hist_k[i]);
  float sfk = E4M3_MAX / ak;
  if (!(ak > 0.f && isfinite(ak))) sfk = 1.f / scale_k[0];
  float sk = 1.f / sfk;
  scales[0] = sx;
  scales[1] = sk;
  scales[2] = sx * sk;
}

// Tile layout (both operands), matched to mfma_scale_f32_32x32x64_f8f6f4:
// per (row-block 128 × k-block 64) tile, 8192 B contiguous, as 512 16-B
// chunks c = g*128 + h*64 + l  (g=row-group 0..3, h=k-half 0..1, l=lane):
//   chunk holds op[row = g*32 + (l&31)][k = (l>>5)*32 + h*16 + 0..15]
// => GEMM stages linearly with global_load_lds and reads each lane's
//    32-byte fragment as two conflict-free ds_read_b128 at lane*16.

// ---------------- quantize x -> tiled fp8 A ----------------
__global__ void quant_x_kernel(const float* __restrict__ x,
                               unsigned char* __restrict__ Aq,
                               const float* __restrict__ scales, int K) {
  const float s = scales[0];
  const int kt = blockIdx.x, mt = blockIdx.y, nkt = gridDim.x;
  __shared__ float lt[128][68];
  const int t = threadIdx.x;
  const float* src = x + (size_t)mt * 128 * K + (size_t)kt * 64;
#pragma unroll
  for (int it = 0; it < 8; ++it) {
    int row = it * 16 + (t >> 4);
    int c4 = (t & 15) * 4;
    float4 v = *(const float4*)&src[(size_t)row * K + c4];
    lt[row][c4 + 0] = v.x; lt[row][c4 + 1] = v.y;
    lt[row][c4 + 2] = v.z; lt[row][c4 + 3] = v.w;
  }
  __syncthreads();
  uint4* out = (uint4*)(Aq + ((size_t)mt * nkt + kt) * 8192);
#pragma unroll
  for (int cc = 0; cc < 2; ++cc) {
    int c = t * 2 + cc;
    int g = c >> 7, h = (c >> 6) & 1, l = c & 63;
    int row = g * 32 + (l & 31);
    int kb = (l >> 5) * 32 + h * 16;
    unsigned int w[4];
#pragma unroll
    for (int q = 0; q < 4; ++q) {
      int b = kb + q * 4;
      int p = 0;
      p = __builtin_amdgcn_cvt_pk_fp8_f32(clip448(lt[row][b+0] / s), clip448(lt[row][b+1] / s), p, false);
      p = __builtin_amdgcn_cvt_pk_fp8_f32(clip448(lt[row][b+2] / s), clip448(lt[row][b+3] / s), p, true);
      w[q] = (unsigned int)p;
    }
    out[c] = make_uint4(w[0], w[1], w[2], w[3]);
  }
}

// ---------------- transpose-quantize W[K][N] -> tiled fp8 B ----------------
__global__ void quant_k_kernel(const float* __restrict__ w,
                               unsigned char* __restrict__ Bq,
                               const float* __restrict__ scales, int N) {
  const float s = scales[1];
  const int kt = blockIdx.x, nt = blockIdx.y, nkt = gridDim.x;
  __shared__ float lt[64][132];
  const int t = threadIdx.x;
  const float* src = w + (size_t)kt * 64 * N + (size_t)nt * 128;
#pragma unroll
  for (int it = 0; it < 8; ++it) {
    int row = it * 8 + (t >> 5);
    int c4 = (t & 31) * 4;
    float4 v = *(const float4*)&src[(size_t)row * N + c4];
    lt[row][c4 + 0] = v.x; lt[row][c4 + 1] = v.y;
    lt[row][c4 + 2] = v.z; lt[row][c4 + 3] = v.w;
  }
  __syncthreads();
  uint4* out = (uint4*)(Bq + ((size_t)nt * nkt + kt) * 8192);
#pragma unroll
  for (int cc = 0; cc < 2; ++cc) {
    int c = t * 2 + cc;
    int g = c >> 7, h = (c >> 6) & 1, l = c & 63;
    int nl = g * 32 + (l & 31);
    int kb = (l >> 5) * 32 + h * 16;
    unsigned int w4[4];
#pragma unroll
    for (int q = 0; q < 4; ++q) {
      int b = kb + q * 4;
      int p = 0;
      p = __builtin_amdgcn_cvt_pk_fp8_f32(clip448(lt[b+0][nl] / s), clip448(lt[b+1][nl] / s), p, false);
      p = __builtin_amdgcn_cvt_pk_fp8_f32(clip448(lt[b+2][nl] / s), clip448(lt[b+3][nl] / s), p, true);
      w4[q] = (unsigned int)p;
    }
    out[c] = make_uint4(w4[0], w4[1], w4[2], w4[3]);
  }
}

// ---------------- MX fp8 GEMM + scale + bias + gelu ----------------
// 128x128 tile, BK=64, 256 threads (4 waves, 2x2 of 32x32 subtiles),
// mfma_scale_f32_32x32x64_f8f6f4 with unit (e8m0=127) block scales.
__global__ __launch_bounds__(256, 3) void gemm_fp8_kernel(
    const unsigned char* __restrict__ Aq, const unsigned char* __restrict__ Bq,
    const float* __restrict__ bias, const float* __restrict__ scales,
    float* __restrict__ C, int M, int N, int K) {
  __shared__ __align__(16) unsigned char lA[8192];
  __shared__ __align__(16) unsigned char lB[8192];
  const float s_xk = scales[2];
  const int nkt = K >> 6;
  const int t = threadIdx.x;
  const int lane = t & 63;
  const int wid = t >> 6;
  const int wm = wid >> 1, wn = wid & 1;

  const unsigned char* ga = Aq + (size_t)blockIdx.y * nkt * 8192 + t * 16;
  const unsigned char* gb = Bq + (size_t)blockIdx.x * nkt * 8192 + t * 16;

  f32x16 acc[2][2];
#pragma unroll
  for (int i = 0; i < 2; ++i)
#pragma unroll
    for (int j = 0; j < 2; ++j)
#pragma unroll
      for (int r = 0; r < 16; ++r) acc[i][j][r] = 0.f;

  for (int kt = 0; kt < nkt; ++kt) {
    gld_lds16(ga,        &lA[wid * 1024]);
    gld_lds16(ga + 4096, &lA[wid * 1024 + 4096]);
    gld_lds16(gb,        &lB[wid * 1024]);
    gld_lds16(gb + 4096, &lB[wid * 1024 + 4096]);
    ga += 8192;
    gb += 8192;
    __syncthreads();

    i32x8 av[2], bv[2];
#pragma unroll
    for (int i = 0; i < 2; ++i) {
      int base = (wm * 2 + i) * 2048 + lane * 16;
      i32x4 lo = *(const i32x4*)&lA[base];
      i32x4 hi = *(const i32x4*)&lA[base + 1024];
      av[i] = __builtin_shufflevector(lo, hi, 0, 1, 2, 3, 4, 5, 6, 7);
    }
#pragma unroll
    for (int j = 0; j < 2; ++j) {
      int base = (wn * 2 + j) * 2048 + lane * 16;
      i32x4 lo = *(const i32x4*)&lB[base];
      i32x4 hi = *(const i32x4*)&lB[base + 1024];
      bv[j] = __builtin_shufflevector(lo, hi, 0, 1, 2, 3, 4, 5, 6, 7);
    }

#pragma unroll
    for (int i = 0; i < 2; ++i)
#pragma unroll
      for (int j = 0; j < 2; ++j)
        acc[i][j] = __builtin_amdgcn_mfma_scale_f32_32x32x64_f8f6f4(
            av[i], bv[j], acc[i][j], 0, 0, 0, 127, 0, 127);
    __syncthreads();
  }

  const int m0 = blockIdx.y * 128;
  const int n0 = blockIdx.x * 128;
  float bb[2];
#pragma unroll
  for (int j = 0; j < 2; ++j) {
    int col = n0 + wn * 64 + j * 32 + (lane & 31);
    bb[j] = __bfloat162float(__float2bfloat16(bias[col]));
  }
#pragma unroll
  for (int i = 0; i < 2; ++i) {
    int rowbase = m0 + wm * 64 + i * 32 + 4 * (lane >> 5);
#pragma unroll
    for (int j = 0; j < 2; ++j) {
      int col = n0 + wn * 64 + j * 32 + (lane & 31);
#pragma unroll
      for (int r = 0; r < 16; ++r) {
        int row = rowbase + (r & 3) + 8 * (r >> 2);
        float v = acc[i][j][r] * s_xk + bb[j];
        float g = 0.5f * v *
                  (1.0f + tanhf(0.7978845608028654f * (v + 0.044715f * v * v * v)));
        C[(size_t)row * N + col] = g;
      }
    }
  }
}

// ---------------- launch ----------------
extern "C" void kernel_launch(void* const* d_in, const int* in_sizes, int n_in,
                              void* d_out, int out_size, void* d_ws, size_t ws_size,
                              hipStream_t stream) {
  const float* inputs = (const float*)d_in[0];
  const float* kernelw = (const float*)d_in[1];
  const float* bias = (const float*)d_in[2];
  const float* input_scale = (const float*)d_in[3];
  const float* input_hist = (const float*)d_in[4];
  const float* kernel_scale = (const float*)d_in[5];
  const float* kernel_hist = (const float*)d_in[6];

  const int F = in_sizes[2];             // 16384
  const int D = in_sizes[1] / F;         // 4096
  const long M = (long)in_sizes[0] / D;  // 8192
  const int HL = in_sizes[4];            // 16
  const int N = F, K = D;

  unsigned int* amax = (unsigned int*)d_ws;
  float* scales = (float*)((char*)d_ws + 16);
  unsigned char* Aq = (unsigned char*)d_ws + 64;
  unsigned char* Bq = Aq + (size_t)M * K;

  float* C = (float*)d_out;

  init_ws_kernel<<<1, 1, 0, stream>>>(amax);
  amax_kernel<<<2048, 256, 0, stream>>>(inputs, (long)M * K / 4, &amax[0]);
  amax_kernel<<<2048, 256, 0, stream>>>(kernelw, (long)K * N / 4, &amax[1]);
  scale_kernel<<<1, 64, 0, stream>>>(amax, input_scale, input_hist, kernel_scale,
                                     kernel_hist, HL, scales);
  quant_x_kernel<<<dim3(K / 64, M / 128), 256, 0, stream>>>(inputs, Aq, scales, K);
  quant_k_kernel<<<dim3(K / 64, N / 128), 256, 0, stream>>>(kernelw, Bq, scales, N);
  gemm_fp8_kernel<<<dim3(N / 128, M / 128), 256, 0, stream>>>(Aq, Bq, bias, scales, C,
                                                              (int)M, N, K);
}

// Round 4
// 779.042 us; speedup vs baseline: 2.5903x; 1.0857x over previous
//
#include <hip/hip_runtime.h>
#include <hip/hip_bf16.h>

typedef __attribute__((ext_vector_type(4))) int i32x4;
typedef __attribute__((ext_vector_type(8))) int i32x8;
typedef __attribute__((ext_vector_type(16))) float f32x16;

#define E4M3_MAX 448.0f
#define AS1 __attribute__((address_space(1)))
#define AS3 __attribute__((address_space(3)))

__device__ __forceinline__ float clip448(float v) {
  return fminf(fmaxf(v, -E4M3_MAX), E4M3_MAX);
}

__device__ __forceinline__ void gld_lds16(const void* g, void* l) {
  __builtin_amdgcn_global_load_lds((const AS1 void*)g, (AS3 void*)l, 16, 0, 0);
}

__device__ __forceinline__ float gelu_f(float v) {
  float y = 0.7978845608028654f * (v + 0.044715f * v * v * v);
  float a = fabsf(y);
  float z = __expf(-2.f * a);          // z in (0,1], no overflow
  float th = (1.f - z) / (1.f + z);    // tanh(|y|)
  th = copysignf(th, y);
  return 0.5f * v * (1.f + th);
}

// ---------------- init ----------------
__global__ void init_ws_kernel(unsigned int* amax) {
  amax[0] = 0u;
  amax[1] = 0u;
}

// ---------------- amax reduction ----------------
__global__ void amax_kernel(const float* __restrict__ x, long n4,
                            unsigned int* __restrict__ amax_out) {
  long i0 = (long)blockIdx.x * blockDim.x + threadIdx.x;
  long stride = (long)gridDim.x * blockDim.x;
  const float4* x4 = (const float4*)x;
  float m = 0.f;
  for (long i = i0; i < n4; i += stride) {
    float4 v = x4[i];
    m = fmaxf(m, fmaxf(fmaxf(fabsf(v.x), fabsf(v.y)), fmaxf(fabsf(v.z), fabsf(v.w))));
  }
#pragma unroll
  for (int off = 32; off >= 1; off >>= 1)
    m = fmaxf(m, __shfl_xor(m, off));
  __shared__ float wmax[8];
  int wid = threadIdx.x >> 6;
  if ((threadIdx.x & 63) == 0) wmax[wid] = m;
  __syncthreads();
  if (threadIdx.x == 0) {
    int nw = blockDim.x >> 6;
    float bm = wmax[0];
    for (int w = 1; w < nw; ++w) bm = fmaxf(bm, wmax[w]);
    atomicMax(amax_out, __float_as_uint(bm));  // vals >= 0: uint order == float order
  }
}

// ---------------- delayed-scaling scale computation ----------------
__global__ void scale_kernel(const unsigned int* __restrict__ amax,
                             const float* __restrict__ scale_x,
                             const float* __restrict__ hist_x,
                             const float* __restrict__ scale_k,
                             const float* __restrict__ hist_k,
                             int hl, float* __restrict__ scales) {
  if (threadIdx.x != 0) return;
  float ax = __uint_as_float(amax[0]);
  for (int i = 0; i < hl - 1; ++i) ax = fmaxf(ax, hist_x[i]);
  float sfx = E4M3_MAX / ax;
  if (!(ax > 0.f && isfinite(ax))) sfx = 1.f / scale_x[0];
  float sx = 1.f / sfx;
  float ak = __uint_as_float(amax[1]);
  for (int i = 0; i < hl - 1; ++i) ak = fmaxf(ak, hist_k[i]);
  float sfk = E4M3_MAX / ak;
  if (!(ak > 0.f && isfinite(ak))) sfk = 1.f / scale_k[0];
  float sk = 1.f / sfk;
  scales[0] = sx;
  scales[1] = sk;
  scales[2] = sx * sk;
}

// Tile layout (both operands), matched to mfma_scale_f32_32x32x64_f8f6f4:
// per (row-block 128 × k-block 64) tile, 8192 B contiguous, as 512 16-B
// chunks c = g*128 + h*64 + l  (g=row-group 0..3, h=k-half 0..1, l=lane):
//   chunk holds op[row = g*32 + (l&31)][k = (l>>5)*32 + h*16 + 0..15]
// => GEMM stages linearly with global_load_lds and reads each lane's
//    32-byte fragment as two conflict-free ds_read_b128 at lane*16.

// ---------------- quantize x -> tiled fp8 A ----------------
__global__ void quant_x_kernel(const float* __restrict__ x,
                               unsigned char* __restrict__ Aq,
                               const float* __restrict__ scales, int K) {
  const float s = scales[0];
  const int kt = blockIdx.x, mt = blockIdx.y, nkt = gridDim.x;
  __shared__ float lt[128][68];
  const int t = threadIdx.x;
  const float* src = x + (size_t)mt * 128 * K + (size_t)kt * 64;
#pragma unroll
  for (int it = 0; it < 8; ++it) {
    int row = it * 16 + (t >> 4);
    int c4 = (t & 15) * 4;
    float4 v = *(const float4*)&src[(size_t)row * K + c4];
    lt[row][c4 + 0] = v.x; lt[row][c4 + 1] = v.y;
    lt[row][c4 + 2] = v.z; lt[row][c4 + 3] = v.w;
  }
  __syncthreads();
  uint4* out = (uint4*)(Aq + ((size_t)mt * nkt + kt) * 8192);
#pragma unroll
  for (int cc = 0; cc < 2; ++cc) {
    int c = t * 2 + cc;
    int g = c >> 7, h = (c >> 6) & 1, l = c & 63;
    int row = g * 32 + (l & 31);
    int kb = (l >> 5) * 32 + h * 16;
    unsigned int w[4];
#pragma unroll
    for (int q = 0; q < 4; ++q) {
      int b = kb + q * 4;
      int p = 0;
      p = __builtin_amdgcn_cvt_pk_fp8_f32(clip448(lt[row][b+0] / s), clip448(lt[row][b+1] / s), p, false);
      p = __builtin_amdgcn_cvt_pk_fp8_f32(clip448(lt[row][b+2] / s), clip448(lt[row][b+3] / s), p, true);
      w[q] = (unsigned int)p;
    }
    out[c] = make_uint4(w[0], w[1], w[2], w[3]);
  }
}

// ---------------- transpose-quantize W[K][N] -> tiled fp8 B ----------------
__global__ void quant_k_kernel(const float* __restrict__ w,
                               unsigned char* __restrict__ Bq,
                               const float* __restrict__ scales, int N) {
  const float s = scales[1];
  const int kt = blockIdx.x, nt = blockIdx.y, nkt = gridDim.x;
  __shared__ float lt[64][132];
  const int t = threadIdx.x;
  const float* src = w + (size_t)kt * 64 * N + (size_t)nt * 128;
#pragma unroll
  for (int it = 0; it < 8; ++it) {
    int row = it * 8 + (t >> 5);
    int c4 = (t & 31) * 4;
    float4 v = *(const float4*)&src[(size_t)row * N + c4];
    lt[row][c4 + 0] = v.x; lt[row][c4 + 1] = v.y;
    lt[row][c4 + 2] = v.z; lt[row][c4 + 3] = v.w;
  }
  __syncthreads();
  uint4* out = (uint4*)(Bq + ((size_t)nt * nkt + kt) * 8192);
#pragma unroll
  for (int cc = 0; cc < 2; ++cc) {
    int c = t * 2 + cc;
    int g = c >> 7, h = (c >> 6) & 1, l = c & 63;
    int nl = g * 32 + (l & 31);
    int kb = (l >> 5) * 32 + h * 16;
    unsigned int w4[4];
#pragma unroll
    for (int q = 0; q < 4; ++q) {
      int b = kb + q * 4;
      int p = 0;
      p = __builtin_amdgcn_cvt_pk_fp8_f32(clip448(lt[b+0][nl] / s), clip448(lt[b+1][nl] / s), p, false);
      p = __builtin_amdgcn_cvt_pk_fp8_f32(clip448(lt[b+2][nl] / s), clip448(lt[b+3][nl] / s), p, true);
      w4[q] = (unsigned int)p;
    }
    out[c] = make_uint4(w4[0], w4[1], w4[2], w4[3]);
  }
}

// ---------------- MX fp8 GEMM + scale + bias + gelu ----------------
// 256x256 tile, BK=64, 512 threads (8 waves, 2Mx4N of 128x64 per wave),
// double-buffered LDS with counted vmcnt (T3/T4) + setprio (T5).
__global__ __launch_bounds__(512, 2) void gemm_fp8_kernel(
    const unsigned char* __restrict__ Aq, const unsigned char* __restrict__ Bq,
    const float* __restrict__ bias, const float* __restrict__ scales,
    float* __restrict__ C, int M, int N, int K) {
  __shared__ __align__(16) unsigned char lds[65536];  // 2 bufs x (16K A + 16K B)
  const float s_xk = scales[2];
  const int nkt = K >> 6;
  const int t = threadIdx.x;
  const int lane = t & 63;
  const int wid = t >> 6;
  const int wm = wid >> 2, wn = wid & 3;

  // XCD-aware bijective swizzle (nwg = 2048, divisible by 8)
  int f = blockIdx.y * gridDim.x + blockIdx.x;
  int cpx = (gridDim.x * gridDim.y) >> 3;
  int f2 = (f & 7) * cpx + (f >> 3);
  int bx = f2 % gridDim.x;
  int by = f2 / gridDim.x;

  const size_t strideT = (size_t)nkt * 8192;  // one 128-row tile stream
  const unsigned char* gA = Aq + (size_t)(2 * by) * strideT + t * 16;
  const unsigned char* gB = Bq + (size_t)(2 * bx) * strideT + t * 16;

  f32x16 acc[4][2];
#pragma unroll
  for (int i = 0; i < 4; ++i)
#pragma unroll
    for (int j = 0; j < 2; ++j)
#pragma unroll
      for (int r = 0; r < 16; ++r) acc[i][j][r] = 0.f;

  auto stage = [&](int buf, int kt_) {
    size_t o = (size_t)kt_ * 8192;
    unsigned char* l = lds + buf * 32768 + wid * 1024;
    gld_lds16(gA + o,           l);
    gld_lds16(gA + strideT + o, l + 8192);
    gld_lds16(gB + o,           l + 16384);
    gld_lds16(gB + strideT + o, l + 24576);
  };

  auto compute = [&](int buf) {
    const unsigned char* la = lds + buf * 32768;
    const unsigned char* lb = la + 16384;
    i32x8 av[4], bv[2];
#pragma unroll
    for (int i = 0; i < 4; ++i) {
      int g = wm * 4 + i;
      i32x4 lo = *(const i32x4*)&la[g * 2048 + lane * 16];
      i32x4 hi = *(const i32x4*)&la[g * 2048 + 1024 + lane * 16];
      av[i] = __builtin_shufflevector(lo, hi, 0, 1, 2, 3, 4, 5, 6, 7);
    }
#pragma unroll
    for (int j = 0; j < 2; ++j) {
      int g = wn * 2 + j;
      i32x4 lo = *(const i32x4*)&lb[g * 2048 + lane * 16];
      i32x4 hi = *(const i32x4*)&lb[g * 2048 + 1024 + lane * 16];
      bv[j] = __builtin_shufflevector(lo, hi, 0, 1, 2, 3, 4, 5, 6, 7);
    }
    __builtin_amdgcn_s_setprio(1);
#pragma unroll
    for (int i = 0; i < 4; ++i)
#pragma unroll
      for (int j = 0; j < 2; ++j)
        acc[i][j] = __builtin_amdgcn_mfma_scale_f32_32x32x64_f8f6f4(
            av[i], bv[j], acc[i][j], 0, 0, 0, 127, 0, 127);
    __builtin_amdgcn_s_setprio(0);
  };

  stage(0, 0);
  int buf = 0;
  for (int kt = 0; kt < nkt - 1; ++kt) {
    stage(buf ^ 1, kt + 1);                          // next tile: stays in flight
    asm volatile("s_waitcnt vmcnt(4)" ::: "memory"); // counted: only cur's 4 drained
    __builtin_amdgcn_s_barrier();
    asm volatile("" ::: "memory");
    compute(buf);
    asm volatile("" ::: "memory");
    __builtin_amdgcn_s_barrier();                    // reads done before overwrite
    buf ^= 1;
  }
  asm volatile("s_waitcnt vmcnt(0)" ::: "memory");
  __builtin_amdgcn_s_barrier();
  asm volatile("" ::: "memory");
  compute(buf);

  // epilogue: scale, bias (bf16-rounded), fast tanh-gelu
  const int m0 = by * 256;
  const int n0 = bx * 256;
  float bb[2];
#pragma unroll
  for (int j = 0; j < 2; ++j) {
    int col = n0 + wn * 64 + j * 32 + (lane & 31);
    bb[j] = __bfloat162float(__float2bfloat16(bias[col]));
  }
#pragma unroll
  for (int i = 0; i < 4; ++i) {
    int rowbase = m0 + wm * 128 + i * 32 + 4 * (lane >> 5);
#pragma unroll
    for (int j = 0; j < 2; ++j) {
      int col = n0 + wn * 64 + j * 32 + (lane & 31);
#pragma unroll
      for (int r = 0; r < 16; ++r) {
        int row = rowbase + (r & 3) + 8 * (r >> 2);
        float v = acc[i][j][r] * s_xk + bb[j];
        C[(size_t)row * N + col] = gelu_f(v);
      }
    }
  }
}

// ---------------- launch ----------------
extern "C" void kernel_launch(void* const* d_in, const int* in_sizes, int n_in,
                              void* d_out, int out_size, void* d_ws, size_t ws_size,
                              hipStream_t stream) {
  const float* inputs = (const float*)d_in[0];
  const float* kernelw = (const float*)d_in[1];
  const float* bias = (const float*)d_in[2];
  const float* input_scale = (const float*)d_in[3];
  const float* input_hist = (const float*)d_in[4];
  const float* kernel_scale = (const float*)d_in[5];
  const float* kernel_hist = (const float*)d_in[6];

  const int F = in_sizes[2];             // 16384
  const int D = in_sizes[1] / F;         // 4096
  const long M = (long)in_sizes[0] / D;  // 8192
  const int HL = in_sizes[4];            // 16
  const int N = F, K = D;

  unsigned int* amax = (unsigned int*)d_ws;
  float* scales = (float*)((char*)d_ws + 16);
  unsigned char* Aq = (unsigned char*)d_ws + 64;
  unsigned char* Bq = Aq + (size_t)M * K;

  float* C = (float*)d_out;

  init_ws_kernel<<<1, 1, 0, stream>>>(amax);
  amax_kernel<<<2048, 256, 0, stream>>>(inputs, (long)M * K / 4, &amax[0]);
  amax_kernel<<<2048, 256, 0, stream>>>(kernelw, (long)K * N / 4, &amax[1]);
  scale_kernel<<<1, 64, 0, stream>>>(amax, input_scale, input_hist, kernel_scale,
                                     kernel_hist, HL, scales);
  quant_x_kernel<<<dim3(K / 64, M / 128), 256, 0, stream>>>(inputs, Aq, scales, K);
  quant_k_kernel<<<dim3(K / 64, N / 128), 256, 0, stream>>>(kernelw, Bq, scales, N);
  gemm_fp8_kernel<<<dim3(N / 256, M / 256), 512, 0, stream>>>(Aq, Bq, bias, scales, C,
                                                              (int)M, N, K);
}